// Round 1
// baseline (743.391 us; speedup 1.0000x reference)
//
#include <hip/hip_runtime.h>
#include <hip/hip_bf16.h>

// ---------- helpers ----------
typedef __attribute__((ext_vector_type(8))) short bf16x8;
typedef __attribute__((ext_vector_type(4))) float f32x4;

static __device__ __forceinline__ short f2bf(float f) {
    unsigned u = __float_as_uint(f);
    unsigned r = (u + 0x7FFFu + ((u >> 16) & 1u)) >> 16;  // RNE truncate to bf16
    return (short)(unsigned short)r;
}

// ---------- degree / norm ----------
__global__ void deg_kernel(const int* __restrict__ src, const int* __restrict__ dst,
                           int* __restrict__ deg_out, int* __restrict__ deg_in, int E) {
    int e = blockIdx.x * blockDim.x + threadIdx.x;
    if (e < E) {
        atomicAdd(&deg_out[src[e]], 1);
        atomicAdd(&deg_in[dst[e]], 1);
    }
}

__global__ void norm_kernel(const int* __restrict__ deg_out, const int* __restrict__ deg_in,
                            float* __restrict__ ns, float* __restrict__ nd, int N) {
    int i = blockIdx.x * blockDim.x + threadIdx.x;
    if (i < N) {
        ns[i] = rsqrtf((float)max(deg_out[i], 1));
        nd[i] = rsqrtf((float)max(deg_in[i], 1));
    }
}

// ---------- exclusive scan of deg_in -> offsets (single block, 2-pass chunked) ----------
__global__ __launch_bounds__(1024) void scan_kernel(const int* __restrict__ deg,
                                                    int* __restrict__ offsets, int N) {
    __shared__ int sdata[1024];
    const int tid = threadIdx.x;
    const int items = (N + 1023) >> 10;
    const int start = tid * items;
    int s = 0;
    for (int j = 0; j < items; j++) {
        int i = start + j;
        s += (i < N) ? deg[i] : 0;
    }
    sdata[tid] = s;
    __syncthreads();
    for (int off = 1; off < 1024; off <<= 1) {
        int t = (tid >= off) ? sdata[tid - off] : 0;
        __syncthreads();
        sdata[tid] += t;
        __syncthreads();
    }
    int run = sdata[tid] - s;  // exclusive prefix of this thread's chunk
    for (int j = 0; j < items; j++) {
        int i = start + j;
        if (i < N) { offsets[i] = run; run += deg[i]; }
    }
    if (tid == 1023) offsets[N] = run;  // == E
}

// ---------- scatter edges into CSR-by-dst buckets ----------
__global__ void scatter_kernel(const int* __restrict__ src, const int* __restrict__ dst,
                               const int* __restrict__ offsets, int* __restrict__ cursor,
                               int* __restrict__ bucket, int E) {
    int e = blockIdx.x * blockDim.x + threadIdx.x;
    if (e < E) {
        int d = dst[e];
        int p = atomicAdd(&cursor[d], 1);
        bucket[offsets[d] + p] = src[e];
    }
}

// ---------- W1 [K=1024][N=256] fp32 -> Wt [n][k] bf16 (transposed, k-contiguous) ----------
__global__ __launch_bounds__(1024) void transpose_w1(const float* __restrict__ W1,
                                                     short* __restrict__ Wt) {
    __shared__ short tile[32][33];
    int k0 = blockIdx.x * 32, n0 = blockIdx.y * 32;
    int tx = threadIdx.x & 31, ty = threadIdx.x >> 5;
    tile[ty][tx] = f2bf(W1[(size_t)(k0 + ty) * 256 + (n0 + tx)]);
    __syncthreads();
    Wt[(size_t)(n0 + ty) * 1024 + (k0 + tx)] = tile[tx][ty];
}

// ---------- GEMM1: h = (x @ W1) * norm_src[row], bf16 MFMA ----------
#define BM 128
#define BN 128
#define BK 32
#define LSTR 56  // LDS row stride in bf16 elems: 112B = 28 dwords -> 2-way bank aliasing (free)

__global__ __launch_bounds__(256) void gemm1_kernel(const float* __restrict__ x,
                                                    const short* __restrict__ Wt,
                                                    const float* __restrict__ norm_src,
                                                    float* __restrict__ h, int M) {
    __shared__ __align__(16) short As[BM * LSTR];
    __shared__ __align__(16) short Bs[BN * LSTR];
    const int tid  = threadIdx.x;
    const int lane = tid & 63;
    const int wave = tid >> 6;
    const int quad = lane >> 4;
    const int mrow = lane & 15;
    const int wm = (wave >> 1) * 64;
    const int wn = (wave & 1) * 64;
    const int bm = blockIdx.x * BM;
    const int bn = blockIdx.y * BN;

    f32x4 acc[4][4] = {};

    const int ar = tid >> 3;  // 0..31 (A stage row base)
    const int ac = tid & 7;   // float4 column

    for (int k0 = 0; k0 < 1024; k0 += BK) {
        // stage A (fp32 -> bf16)
#pragma unroll
        for (int i = 0; i < 4; i++) {
            int r = ar + i * 32;
            int gr = bm + r;
            float4 v = make_float4(0.f, 0.f, 0.f, 0.f);
            if (gr < M) v = *(const float4*)(x + (size_t)gr * 1024 + k0 + ac * 4);
            short4 b;
            b.x = f2bf(v.x); b.y = f2bf(v.y); b.z = f2bf(v.z); b.w = f2bf(v.w);
            *(short4*)&As[r * LSTR + ac * 4] = b;
        }
        // stage B (already bf16, k-contiguous)
#pragma unroll
        for (int i = 0; i < 2; i++) {
            int chunk = tid + i * 256;
            int r = chunk >> 2;
            int c = chunk & 3;
            int4 v = *(const int4*)(Wt + (size_t)(bn + r) * 1024 + k0 + c * 8);
            *(int4*)&Bs[r * LSTR + c * 8] = v;
        }
        __syncthreads();

        bf16x8 af[4], bfr[4];
#pragma unroll
        for (int mi = 0; mi < 4; mi++)
            af[mi] = *(bf16x8*)&As[(wm + mi * 16 + mrow) * LSTR + quad * 8];
#pragma unroll
        for (int ni = 0; ni < 4; ni++)
            bfr[ni] = *(bf16x8*)&Bs[(wn + ni * 16 + mrow) * LSTR + quad * 8];
#pragma unroll
        for (int mi = 0; mi < 4; mi++)
#pragma unroll
            for (int ni = 0; ni < 4; ni++)
                acc[mi][ni] = __builtin_amdgcn_mfma_f32_16x16x32_bf16(af[mi], bfr[ni], acc[mi][ni], 0, 0, 0);
        __syncthreads();
    }

    // epilogue: scale by norm_src[row], store fp32
#pragma unroll
    for (int mi = 0; mi < 4; mi++) {
        int rbase = bm + wm + mi * 16 + quad * 4;
#pragma unroll
        for (int ni = 0; ni < 4; ni++) {
            int c = bn + wn + ni * 16 + mrow;
#pragma unroll
            for (int reg = 0; reg < 4; reg++) {
                int rr = rbase + reg;
                if (rr < M) h[(size_t)rr * 256 + c] = acc[mi][ni][reg] * norm_src[rr];
            }
        }
    }
}

// ---------- agg1 fused with layer-2 projection ----------
// One wave per dst node: sum gathered h rows, norm+bias+relu in regs, dot W2, write z.
__global__ __launch_bounds__(256) void agg1_kernel(const float* __restrict__ h,
                                                   const int* __restrict__ bucket,
                                                   const int* __restrict__ offsets,
                                                   const float* __restrict__ norm_dst,
                                                   const float* __restrict__ norm_src,
                                                   const float* __restrict__ b1,
                                                   const float* __restrict__ W2,
                                                   float* __restrict__ z, int N) {
    int wave = threadIdx.x >> 6;
    int lane = threadIdx.x & 63;
    int node = blockIdx.x * 4 + wave;
    if (node >= N) return;
    int beg = offsets[node], end = offsets[node + 1];
    float4 acc = make_float4(0.f, 0.f, 0.f, 0.f);
    for (int e = beg; e < end; e++) {
        int s = bucket[e];
        const float4 v = *(const float4*)(h + (size_t)s * 256 + lane * 4);
        acc.x += v.x; acc.y += v.y; acc.z += v.z; acc.w += v.w;
    }
    float nd = norm_dst[node];
    float4 bb = *(const float4*)(b1 + lane * 4);
    float4 o;
    o.x = fmaxf(acc.x * nd + bb.x, 0.f);
    o.y = fmaxf(acc.y * nd + bb.y, 0.f);
    o.z = fmaxf(acc.z * nd + bb.z, 0.f);
    o.w = fmaxf(acc.w * nd + bb.w, 0.f);
    // layer-2 projection: dot(h1_row, W2) * norm_src[node]
    float4 w = *(const float4*)(W2 + lane * 4);
    float p = o.x * w.x + o.y * w.y + o.z * w.z + o.w * w.w;
#pragma unroll
    for (int off = 32; off > 0; off >>= 1) p += __shfl_xor(p, off, 64);
    if (lane == 0) z[node] = p * norm_src[node];
}

// ---------- agg2: out = relu(norm_dst * sum z[src] + b2) ----------
__global__ void agg2_kernel(const float* __restrict__ z, const int* __restrict__ bucket,
                            const int* __restrict__ offsets, const float* __restrict__ norm_dst,
                            const float* __restrict__ b2, float* __restrict__ out, int N) {
    int i = blockIdx.x * blockDim.x + threadIdx.x;
    if (i >= N) return;
    int beg = offsets[i], end = offsets[i + 1];
    float s = 0.f;
    for (int e = beg; e < end; e++) s += z[bucket[e]];
    out[i] = fmaxf(s * norm_dst[i] + b2[0], 0.f);
}

extern "C" void kernel_launch(void* const* d_in, const int* in_sizes, int n_in,
                              void* d_out, int out_size, void* d_ws, size_t ws_size,
                              hipStream_t stream) {
    const int D_HID = in_sizes[4];           // 256
    const int D_IN  = in_sizes[3] / D_HID;   // 1024
    const int N     = in_sizes[0] / D_IN;    // 50000
    const int E     = in_sizes[1];           // 800000

    const float* x   = (const float*)d_in[0];
    const int*   src = (const int*)d_in[1];
    const int*   dst = (const int*)d_in[2];
    const float* W1  = (const float*)d_in[3];
    const float* b1  = (const float*)d_in[4];
    const float* W2  = (const float*)d_in[5];
    const float* b2  = (const float*)d_in[6];
    float* out = (float*)d_out;

    // carve workspace (256B aligned regions)
    char* p = (char*)d_ws;
    auto alloc = [&](size_t bytes) {
        void* r = (void*)p;
        p += (bytes + 255) & ~(size_t)255;
        return r;
    };
    int*   deg_out  = (int*)alloc((size_t)N * 4);
    int*   deg_in   = (int*)alloc((size_t)N * 4);
    int*   cursor   = (int*)alloc((size_t)N * 4);
    float* norm_src = (float*)alloc((size_t)N * 4);
    float* norm_dst = (float*)alloc((size_t)N * 4);
    int*   offsets  = (int*)alloc((size_t)(N + 1) * 4);
    int*   bucket   = (int*)alloc((size_t)E * 4);
    short* Wt       = (short*)alloc((size_t)D_IN * D_HID * 2);
    float* h        = (float*)alloc((size_t)N * D_HID * 4);
    float* z        = (float*)alloc((size_t)N * 4);

    hipMemsetAsync(deg_out, 0, (size_t)N * 4, stream);
    hipMemsetAsync(deg_in,  0, (size_t)N * 4, stream);
    hipMemsetAsync(cursor,  0, (size_t)N * 4, stream);

    deg_kernel<<<(E + 255) / 256, 256, 0, stream>>>(src, dst, deg_out, deg_in, E);
    norm_kernel<<<(N + 255) / 256, 256, 0, stream>>>(deg_out, deg_in, norm_src, norm_dst, N);
    scan_kernel<<<1, 1024, 0, stream>>>(deg_in, offsets, N);
    scatter_kernel<<<(E + 255) / 256, 256, 0, stream>>>(src, dst, offsets, cursor, bucket, E);
    transpose_w1<<<dim3(D_IN / 32, D_HID / 32), 1024, 0, stream>>>(W1, Wt);
    gemm1_kernel<<<dim3((N + BM - 1) / BM, D_HID / BN), 256, 0, stream>>>(x, Wt, norm_src, h, N);
    agg1_kernel<<<(N + 3) / 4, 256, 0, stream>>>(h, bucket, offsets, norm_dst, norm_src, b1, W2, z, N);
    agg2_kernel<<<(N + 255) / 256, 256, 0, stream>>>(z, bucket, offsets, norm_dst, b2, out, N);
}

// Round 2
// 692.498 us; speedup vs baseline: 1.0735x; 1.0735x over previous
//
#include <hip/hip_runtime.h>
#include <hip/hip_bf16.h>

// ---------- helpers ----------
typedef __attribute__((ext_vector_type(8))) short bf16x8;
typedef __attribute__((ext_vector_type(4))) float f32x4;

static __device__ __forceinline__ short f2bf(float f) {
    unsigned u = __float_as_uint(f);
    unsigned r = (u + 0x7FFFu + ((u >> 16) & 1u)) >> 16;  // RNE truncate to bf16
    return (short)(unsigned short)r;
}
static __device__ __forceinline__ float bf2f(short s) {
    return __uint_as_float(((unsigned)(unsigned short)s) << 16);
}

// ---------- degree / norm ----------
__global__ void deg_kernel(const int* __restrict__ src, const int* __restrict__ dst,
                           int* __restrict__ deg_out, int* __restrict__ deg_in, int E) {
    int e = blockIdx.x * blockDim.x + threadIdx.x;
    if (e < E) {
        atomicAdd(&deg_out[src[e]], 1);
        atomicAdd(&deg_in[dst[e]], 1);
    }
}

__global__ void norm_kernel(const int* __restrict__ deg_out, const int* __restrict__ deg_in,
                            float* __restrict__ ns, float* __restrict__ nd, int N) {
    int i = blockIdx.x * blockDim.x + threadIdx.x;
    if (i < N) {
        ns[i] = rsqrtf((float)max(deg_out[i], 1));
        nd[i] = rsqrtf((float)max(deg_in[i], 1));
    }
}

// ---------- exclusive scan of deg_in -> offsets (single block, 2-pass chunked) ----------
__global__ __launch_bounds__(1024) void scan_kernel(const int* __restrict__ deg,
                                                    int* __restrict__ offsets, int N) {
    __shared__ int sdata[1024];
    const int tid = threadIdx.x;
    const int items = (N + 1023) >> 10;
    const int start = tid * items;
    int s = 0;
    for (int j = 0; j < items; j++) {
        int i = start + j;
        s += (i < N) ? deg[i] : 0;
    }
    sdata[tid] = s;
    __syncthreads();
    for (int off = 1; off < 1024; off <<= 1) {
        int t = (tid >= off) ? sdata[tid - off] : 0;
        __syncthreads();
        sdata[tid] += t;
        __syncthreads();
    }
    int run = sdata[tid] - s;  // exclusive prefix of this thread's chunk
    for (int j = 0; j < items; j++) {
        int i = start + j;
        if (i < N) { offsets[i] = run; run += deg[i]; }
    }
    if (tid == 1023) offsets[N] = run;  // == E
}

// ---------- scatter edges into CSR-by-dst buckets ----------
__global__ void scatter_kernel(const int* __restrict__ src, const int* __restrict__ dst,
                               const int* __restrict__ offsets, int* __restrict__ cursor,
                               int* __restrict__ bucket, int E) {
    int e = blockIdx.x * blockDim.x + threadIdx.x;
    if (e < E) {
        int d = dst[e];
        int p = atomicAdd(&cursor[d], 1);
        bucket[offsets[d] + p] = src[e];
    }
}

// ---------- W1 [K=1024][N=256] fp32 -> Wt [n][k] bf16 (transposed, k-contiguous) ----------
__global__ __launch_bounds__(1024) void transpose_w1(const float* __restrict__ W1,
                                                     short* __restrict__ Wt) {
    __shared__ short tile[32][33];
    int k0 = blockIdx.x * 32, n0 = blockIdx.y * 32;
    int tx = threadIdx.x & 31, ty = threadIdx.x >> 5;
    tile[ty][tx] = f2bf(W1[(size_t)(k0 + ty) * 256 + (n0 + tx)]);
    __syncthreads();
    Wt[(size_t)(n0 + ty) * 1024 + (k0 + tx)] = tile[tx][ty];
}

// ---------- GEMM1: h_bf16 = (x @ W1) * norm_src[row], bf16 MFMA ----------
// Register-prefetch pipeline: tile k+1's global loads are issued right after
// the barrier so their ~900-cyc latency overlaps ds_read+MFMA of tile k.
#define BM 128
#define BN 128
#define BK 32
#define LSTR 56  // LDS row stride in bf16 elems: 28 dwords -> 2-way bank aliasing (free, m136)

__global__ __launch_bounds__(256) void gemm1_kernel(const float* __restrict__ x,
                                                    const short* __restrict__ Wt,
                                                    const float* __restrict__ norm_src,
                                                    short* __restrict__ hb, int M) {
    __shared__ __align__(16) short As[BM * LSTR];
    __shared__ __align__(16) short Bs[BN * LSTR];
    const int tid  = threadIdx.x;
    const int lane = tid & 63;
    const int wave = tid >> 6;
    const int quad = lane >> 4;
    const int mrow = lane & 15;
    const int wm = (wave >> 1) * 64;
    const int wn = (wave & 1) * 64;
    const int bm = blockIdx.x * BM;
    const int bn = blockIdx.y * BN;

    f32x4 acc[4][4] = {};

    const int ar = tid >> 3;  // 0..31 (A stage row base)
    const int ac = tid & 7;   // float4 column
    const int br = tid >> 2;  // 0..63 (B stage row base per 256-chunk)
    const int bc = tid & 3;   // int4 column

    float4 a_reg[4];
    int4   b_reg[2];

    auto load_tile = [&](int k0) {
#pragma unroll
        for (int i = 0; i < 4; i++) {
            int gr = bm + ar + i * 32;
            a_reg[i] = (gr < M) ? *(const float4*)(x + (size_t)gr * 1024 + k0 + ac * 4)
                                : make_float4(0.f, 0.f, 0.f, 0.f);
        }
#pragma unroll
        for (int i = 0; i < 2; i++) {
            int r = br + i * 64;
            b_reg[i] = *(const int4*)(Wt + (size_t)(bn + r) * 1024 + k0 + bc * 8);
        }
    };
    auto store_tile = [&]() {
#pragma unroll
        for (int i = 0; i < 4; i++) {
            short4 b;
            b.x = f2bf(a_reg[i].x); b.y = f2bf(a_reg[i].y);
            b.z = f2bf(a_reg[i].z); b.w = f2bf(a_reg[i].w);
            *(short4*)&As[(ar + i * 32) * LSTR + ac * 4] = b;
        }
#pragma unroll
        for (int i = 0; i < 2; i++) {
            *(int4*)&Bs[(br + i * 64) * LSTR + bc * 8] = b_reg[i];
        }
    };

    load_tile(0);
    for (int k0 = 0; k0 < 1024; k0 += BK) {
        store_tile();
        __syncthreads();
        if (k0 + BK < 1024) load_tile(k0 + BK);  // in flight across this tile's MFMA

        bf16x8 af[4], bfr[4];
#pragma unroll
        for (int mi = 0; mi < 4; mi++)
            af[mi] = *(bf16x8*)&As[(wm + mi * 16 + mrow) * LSTR + quad * 8];
#pragma unroll
        for (int ni = 0; ni < 4; ni++)
            bfr[ni] = *(bf16x8*)&Bs[(wn + ni * 16 + mrow) * LSTR + quad * 8];
#pragma unroll
        for (int mi = 0; mi < 4; mi++)
#pragma unroll
            for (int ni = 0; ni < 4; ni++)
                acc[mi][ni] = __builtin_amdgcn_mfma_f32_16x16x32_bf16(af[mi], bfr[ni], acc[mi][ni], 0, 0, 0);
        __syncthreads();
    }

    // epilogue: scale by norm_src[row], store bf16
#pragma unroll
    for (int mi = 0; mi < 4; mi++) {
        int rbase = bm + wm + mi * 16 + quad * 4;
#pragma unroll
        for (int ni = 0; ni < 4; ni++) {
            int c = bn + wn + ni * 16 + mrow;
#pragma unroll
            for (int reg = 0; reg < 4; reg++) {
                int rr = rbase + reg;
                if (rr < M) hb[(size_t)rr * 256 + c] = f2bf(acc[mi][ni][reg] * norm_src[rr]);
            }
        }
    }
}

// ---------- agg1 fused with layer-2 projection ----------
// One wave per dst node: sum gathered bf16 h rows (lane = 4 cols), norm+bias+relu,
// dot W2, shuffle-reduce, write z.
__global__ __launch_bounds__(256) void agg1_kernel(const short* __restrict__ hb,
                                                   const int* __restrict__ bucket,
                                                   const int* __restrict__ offsets,
                                                   const float* __restrict__ norm_dst,
                                                   const float* __restrict__ norm_src,
                                                   const float* __restrict__ b1,
                                                   const float* __restrict__ W2,
                                                   float* __restrict__ z, int N) {
    int wave = threadIdx.x >> 6;
    int lane = threadIdx.x & 63;
    int node = blockIdx.x * 4 + wave;
    if (node >= N) return;
    int beg = offsets[node], end = offsets[node + 1];
    float a0 = 0.f, a1 = 0.f, a2 = 0.f, a3 = 0.f;
    int e = beg;
    for (; e + 1 < end; e += 2) {  // 2 gathers in flight per iter
        int s0 = bucket[e], s1 = bucket[e + 1];
        short4 v0 = *(const short4*)(hb + (size_t)s0 * 256 + lane * 4);
        short4 v1 = *(const short4*)(hb + (size_t)s1 * 256 + lane * 4);
        a0 += bf2f(v0.x) + bf2f(v1.x);
        a1 += bf2f(v0.y) + bf2f(v1.y);
        a2 += bf2f(v0.z) + bf2f(v1.z);
        a3 += bf2f(v0.w) + bf2f(v1.w);
    }
    if (e < end) {
        short4 v0 = *(const short4*)(hb + (size_t)bucket[e] * 256 + lane * 4);
        a0 += bf2f(v0.x); a1 += bf2f(v0.y); a2 += bf2f(v0.z); a3 += bf2f(v0.w);
    }
    float nd = norm_dst[node];
    float4 bb = *(const float4*)(b1 + lane * 4);
    float o0 = fmaxf(a0 * nd + bb.x, 0.f);
    float o1 = fmaxf(a1 * nd + bb.y, 0.f);
    float o2 = fmaxf(a2 * nd + bb.z, 0.f);
    float o3 = fmaxf(a3 * nd + bb.w, 0.f);
    float4 w = *(const float4*)(W2 + lane * 4);
    float p = o0 * w.x + o1 * w.y + o2 * w.z + o3 * w.w;
#pragma unroll
    for (int off = 32; off > 0; off >>= 1) p += __shfl_xor(p, off, 64);
    if (lane == 0) z[node] = p * norm_src[node];
}

// ---------- agg2: out = relu(norm_dst * sum z[src] + b2) ----------
__global__ void agg2_kernel(const float* __restrict__ z, const int* __restrict__ bucket,
                            const int* __restrict__ offsets, const float* __restrict__ norm_dst,
                            const float* __restrict__ b2, float* __restrict__ out, int N) {
    int i = blockIdx.x * blockDim.x + threadIdx.x;
    if (i >= N) return;
    int beg = offsets[i], end = offsets[i + 1];
    float s = 0.f;
    for (int e = beg; e < end; e++) s += z[bucket[e]];
    out[i] = fmaxf(s * norm_dst[i] + b2[0], 0.f);
}

extern "C" void kernel_launch(void* const* d_in, const int* in_sizes, int n_in,
                              void* d_out, int out_size, void* d_ws, size_t ws_size,
                              hipStream_t stream) {
    const int D_HID = in_sizes[4];           // 256
    const int D_IN  = in_sizes[3] / D_HID;   // 1024
    const int N     = in_sizes[0] / D_IN;    // 50000
    const int E     = in_sizes[1];           // 800000

    const float* x   = (const float*)d_in[0];
    const int*   src = (const int*)d_in[1];
    const int*   dst = (const int*)d_in[2];
    const float* W1  = (const float*)d_in[3];
    const float* b1  = (const float*)d_in[4];
    const float* W2  = (const float*)d_in[5];
    const float* b2  = (const float*)d_in[6];
    float* out = (float*)d_out;

    // carve workspace (256B aligned regions)
    char* p = (char*)d_ws;
    auto alloc = [&](size_t bytes) {
        void* r = (void*)p;
        p += (bytes + 255) & ~(size_t)255;
        return r;
    };
    int*   deg_out  = (int*)alloc((size_t)N * 4);
    int*   deg_in   = (int*)alloc((size_t)N * 4);
    int*   cursor   = (int*)alloc((size_t)N * 4);
    float* norm_src = (float*)alloc((size_t)N * 4);
    float* norm_dst = (float*)alloc((size_t)N * 4);
    int*   offsets  = (int*)alloc((size_t)(N + 1) * 4);
    int*   bucket   = (int*)alloc((size_t)E * 4);
    short* Wt       = (short*)alloc((size_t)D_IN * D_HID * 2);
    short* hb       = (short*)alloc((size_t)N * D_HID * 2);  // h in bf16
    float* z        = (float*)alloc((size_t)N * 4);

    hipMemsetAsync(deg_out, 0, (size_t)N * 4, stream);
    hipMemsetAsync(deg_in,  0, (size_t)N * 4, stream);
    hipMemsetAsync(cursor,  0, (size_t)N * 4, stream);

    deg_kernel<<<(E + 255) / 256, 256, 0, stream>>>(src, dst, deg_out, deg_in, E);
    norm_kernel<<<(N + 255) / 256, 256, 0, stream>>>(deg_out, deg_in, norm_src, norm_dst, N);
    scan_kernel<<<1, 1024, 0, stream>>>(deg_in, offsets, N);
    scatter_kernel<<<(E + 255) / 256, 256, 0, stream>>>(src, dst, offsets, cursor, bucket, E);
    transpose_w1<<<dim3(D_IN / 32, D_HID / 32), 1024, 0, stream>>>(W1, Wt);
    gemm1_kernel<<<dim3((N + BM - 1) / BM, D_HID / BN), 256, 0, stream>>>(x, Wt, norm_src, hb, N);
    agg1_kernel<<<(N + 3) / 4, 256, 0, stream>>>(hb, bucket, offsets, norm_dst, norm_src, b1, W2, z, N);
    agg2_kernel<<<(N + 255) / 256, 256, 0, stream>>>(z, bucket, offsets, norm_dst, b2, out, N);
}

// Round 3
// 506.732 us; speedup vs baseline: 1.4670x; 1.3666x over previous
//
#include <hip/hip_runtime.h>
#include <hip/hip_bf16.h>

// ---------- helpers ----------
typedef __attribute__((ext_vector_type(8))) short bf16x8;
typedef __attribute__((ext_vector_type(4))) float f32x4;

static __device__ __forceinline__ short f2bf(float f) {
    unsigned u = __float_as_uint(f);
    unsigned r = (u + 0x7FFFu + ((u >> 16) & 1u)) >> 16;  // RNE
    return (short)(unsigned short)r;
}
static __device__ __forceinline__ float bf2f(short s) {
    return __uint_as_float(((unsigned)(unsigned short)s) << 16);
}

// async global->LDS, 16B per lane; LDS dest = wave-uniform base + lane*16 (m104)
static __device__ __forceinline__ void gload16(const void* g, void* l) {
    __builtin_amdgcn_global_load_lds((const __attribute__((address_space(1))) unsigned int*)g,
                                     (__attribute__((address_space(3))) unsigned int*)l, 16, 0, 0);
}

// pack 8 fp32 -> bf16x8 (RNE, packed cvt where available)
static __device__ __forceinline__ bf16x8 cvt8(const f32x4 lo, const f32x4 hi) {
    __hip_bfloat162 p0 = __float22bfloat162_rn(make_float2(lo[0], lo[1]));
    __hip_bfloat162 p1 = __float22bfloat162_rn(make_float2(lo[2], lo[3]));
    __hip_bfloat162 p2 = __float22bfloat162_rn(make_float2(hi[0], hi[1]));
    __hip_bfloat162 p3 = __float22bfloat162_rn(make_float2(hi[2], hi[3]));
    short2 s0 = *(short2*)&p0, s1 = *(short2*)&p1, s2 = *(short2*)&p2, s3 = *(short2*)&p3;
    bf16x8 r = {s0.x, s0.y, s1.x, s1.y, s2.x, s2.y, s3.x, s3.y};
    return r;
}

// ---------- degree / norm ----------
__global__ void deg_kernel(const int* __restrict__ src, const int* __restrict__ dst,
                           int* __restrict__ deg_out, int* __restrict__ deg_in, int E) {
    int e = blockIdx.x * blockDim.x + threadIdx.x;
    if (e < E) {
        atomicAdd(&deg_out[src[e]], 1);
        atomicAdd(&deg_in[dst[e]], 1);
    }
}

__global__ void norm_kernel(const int* __restrict__ deg_out, const int* __restrict__ deg_in,
                            float* __restrict__ ns, float* __restrict__ nd, int N) {
    int i = blockIdx.x * blockDim.x + threadIdx.x;
    if (i < N) {
        ns[i] = rsqrtf((float)max(deg_out[i], 1));
        nd[i] = rsqrtf((float)max(deg_in[i], 1));
    }
}

// ---------- 3-phase multi-block exclusive scan of deg_in -> offsets ----------
__global__ void scan_part1(const int* __restrict__ deg, int* __restrict__ bsum, int N) {
    __shared__ int red[256];
    int i = blockIdx.x * 256 + threadIdx.x;
    red[threadIdx.x] = (i < N) ? deg[i] : 0;
    __syncthreads();
    for (int off = 128; off > 0; off >>= 1) {
        if (threadIdx.x < off) red[threadIdx.x] += red[threadIdx.x + off];
        __syncthreads();
    }
    if (threadIdx.x == 0) bsum[blockIdx.x] = red[0];
}

__global__ void scan_part2(const int* __restrict__ bsum, int* __restrict__ bsum_ex, int NB,
                           int* __restrict__ offsets, int N, int E) {
    __shared__ int s[256];
    int t = threadIdx.x;
    int v = (t < NB) ? bsum[t] : 0;
    s[t] = v;
    __syncthreads();
    for (int off = 1; off < 256; off <<= 1) {
        int u = (t >= off) ? s[t - off] : 0;
        __syncthreads();
        s[t] += u;
        __syncthreads();
    }
    bsum_ex[t] = s[t] - v;  // exclusive
    if (t == 0) offsets[N] = E;
}

__global__ void scan_part3(const int* __restrict__ deg, const int* __restrict__ bsum_ex,
                           int* __restrict__ offsets, int N) {
    __shared__ int s[256];
    int t = threadIdx.x, i = blockIdx.x * 256 + t;
    int v = (i < N) ? deg[i] : 0;
    s[t] = v;
    __syncthreads();
    for (int off = 1; off < 256; off <<= 1) {
        int u = (t >= off) ? s[t - off] : 0;
        __syncthreads();
        s[t] += u;
        __syncthreads();
    }
    if (i < N) offsets[i] = bsum_ex[blockIdx.x] + s[t] - v;
}

// ---------- scatter edges into CSR-by-dst buckets ----------
__global__ void scatter_kernel(const int* __restrict__ src, const int* __restrict__ dst,
                               const int* __restrict__ offsets, int* __restrict__ cursor,
                               int* __restrict__ bucket, int E) {
    int e = blockIdx.x * blockDim.x + threadIdx.x;
    if (e < E) {
        int d = dst[e];
        int p = atomicAdd(&cursor[d], 1);
        bucket[offsets[d] + p] = src[e];
    }
}

// ---------- W1 [K=1024][N=256] fp32 -> Wt [n][k] bf16 ----------
__global__ __launch_bounds__(1024) void transpose_w1(const float* __restrict__ W1,
                                                     short* __restrict__ Wt) {
    __shared__ short tile[32][33];
    int k0 = blockIdx.x * 32, n0 = blockIdx.y * 32;
    int tx = threadIdx.x & 31, ty = threadIdx.x >> 5;
    tile[ty][tx] = f2bf(W1[(size_t)(k0 + ty) * 256 + (n0 + tx)]);
    __syncthreads();
    Wt[(size_t)(n0 + ty) * 1024 + (k0 + tx)] = tile[tx][ty];
}

// ---------- GEMM1: hb = bf16((x @ W1) * norm_src[row]) ----------
// m97-style: global_load_lds(16B) staging, A fp32 in LDS (XOR-swizzled chunks),
// cvt->bf16 on read; B bf16 (XOR-swizzled); C staged through LDS for coalesced stores.
#define BM 128
#define BN 128
#define BK 32
#define CSTR 136  // C-staging row stride in shorts (16B-aligned rows)

union SMem {
    struct {
        float A[BM * BK];  // 16 KB, row = 32 floats = 8 chunks of 16B, chunk cp = c ^ (r&7)
        short B[BN * BK];  // 8 KB,  row = 32 shorts = 4 chunks of 16B, chunk cp = c ^ ((n>>1)&3)
    } s;
    short C[BM * CSTR];    // 34 KB epilogue staging
};

__global__ __launch_bounds__(256, 3) void gemm1_kernel(const float* __restrict__ x,
                                                       const short* __restrict__ Wt,
                                                       const float* __restrict__ norm_src,
                                                       short* __restrict__ hb, int M) {
    __shared__ __align__(16) SMem sm;
    __shared__ float ns_lds[BM];
    const int tid  = threadIdx.x;
    const int lane = tid & 63;
    const int wave = tid >> 6;
    const int quad = lane >> 4;
    const int mrow = lane & 15;
    const int wm = (wave >> 1) * 64;
    const int wn = (wave & 1) * 64;
    const int bm = blockIdx.x * BM;
    const int bn = blockIdx.y * BN;

    if (tid < BM) ns_lds[tid] = norm_src[min(bm + tid, M - 1)];

    f32x4 acc[4][4] = {};

    // staging lane roles (constant across k)
    const int aL_r = lane >> 3;                       // 0..7 row within 8-row group
    const int aL_c = (lane & 7) ^ (aL_r & 7);         // global chunk (swizzle)
    const int bL_r = lane >> 2;                       // 0..15 row within 16-row group
    const int bL_c = (lane & 3) ^ ((lane >> 3) & 3);  // global chunk (swizzle)

    for (int k0 = 0; k0 < 1024; k0 += BK) {
        // A: 4 instrs/wave, 8 rows each
#pragma unroll
        for (int i = 0; i < 4; i++) {
            int rowbase = wave * 32 + i * 8;
            int r = rowbase + aL_r;
            if (bm + r < M)
                gload16(x + (size_t)(bm + r) * 1024 + k0 + aL_c * 4, &sm.s.A[rowbase * 32]);
        }
        // B: 2 instrs/wave, 16 rows each
#pragma unroll
        for (int i = 0; i < 2; i++) {
            int nbase = wave * 32 + i * 16;
            int n = nbase + bL_r;
            gload16(Wt + (size_t)(bn + n) * 1024 + k0 + bL_c * 8, &sm.s.B[nbase * 32]);
        }
        __syncthreads();  // drains vmcnt(0): tiles resident

        bf16x8 af[4], bfr[4];
#pragma unroll
        for (int mi = 0; mi < 4; mi++) {
            int row = wm + mi * 16 + mrow;
            f32x4 lo = *(const f32x4*)&sm.s.A[row * 32 + (((quad * 2 + 0) ^ (mrow & 7)) * 4)];
            f32x4 hi = *(const f32x4*)&sm.s.A[row * 32 + (((quad * 2 + 1) ^ (mrow & 7)) * 4)];
            af[mi] = cvt8(lo, hi);
        }
#pragma unroll
        for (int ni = 0; ni < 4; ni++) {
            int n = wn + ni * 16 + mrow;
            bfr[ni] = *(const bf16x8*)&sm.s.B[n * 32 + ((quad ^ ((mrow >> 1) & 3)) * 8)];
        }
#pragma unroll
        for (int mi = 0; mi < 4; mi++)
#pragma unroll
            for (int ni = 0; ni < 4; ni++)
                acc[mi][ni] = __builtin_amdgcn_mfma_f32_16x16x32_bf16(af[mi], bfr[ni], acc[mi][ni], 0, 0, 0);
        __syncthreads();  // all waves done with this tile before overwrite
    }

    // epilogue: acc -> C LDS (scaled, bf16), then coalesced 16B/lane stores
#pragma unroll
    for (int mi = 0; mi < 4; mi++) {
#pragma unroll
        for (int reg = 0; reg < 4; reg++) {
            int row = wm + mi * 16 + quad * 4 + reg;
            float nsv = ns_lds[row];
#pragma unroll
            for (int ni = 0; ni < 4; ni++) {
                int col = wn + ni * 16 + mrow;
                sm.C[row * CSTR + col] = f2bf(acc[mi][ni][reg] * nsv);
            }
        }
    }
    __syncthreads();
#pragma unroll
    for (int j = 0; j < 8; j++) {
        int row = wave * 4 + (lane >> 4) + j * 16;
        int chunk = lane & 15;
        if (bm + row < M) {
            int4 v = *(const int4*)&sm.C[row * CSTR + chunk * 8];
            *(int4*)(hb + (size_t)(bm + row) * 256 + bn + chunk * 8) = v;
        }
    }
}

// ---------- agg1 fused with layer-2 projection ----------
__global__ __launch_bounds__(256) void agg1_kernel(const short* __restrict__ hb,
                                                   const int* __restrict__ bucket,
                                                   const int* __restrict__ offsets,
                                                   const float* __restrict__ norm_dst,
                                                   const float* __restrict__ norm_src,
                                                   const float* __restrict__ b1,
                                                   const float* __restrict__ W2,
                                                   float* __restrict__ z, int N) {
    int wave = threadIdx.x >> 6;
    int lane = threadIdx.x & 63;
    int node = blockIdx.x * 4 + wave;
    if (node >= N) return;
    int beg = offsets[node], end = offsets[node + 1];
    float a0 = 0.f, a1 = 0.f, a2 = 0.f, a3 = 0.f;
    int e = beg;
    for (; e + 3 < end; e += 4) {  // 4 gathers in flight
        int s0 = bucket[e], s1 = bucket[e + 1], s2 = bucket[e + 2], s3 = bucket[e + 3];
        short4 v0 = *(const short4*)(hb + (size_t)s0 * 256 + lane * 4);
        short4 v1 = *(const short4*)(hb + (size_t)s1 * 256 + lane * 4);
        short4 v2 = *(const short4*)(hb + (size_t)s2 * 256 + lane * 4);
        short4 v3 = *(const short4*)(hb + (size_t)s3 * 256 + lane * 4);
        a0 += bf2f(v0.x) + bf2f(v1.x) + bf2f(v2.x) + bf2f(v3.x);
        a1 += bf2f(v0.y) + bf2f(v1.y) + bf2f(v2.y) + bf2f(v3.y);
        a2 += bf2f(v0.z) + bf2f(v1.z) + bf2f(v2.z) + bf2f(v3.z);
        a3 += bf2f(v0.w) + bf2f(v1.w) + bf2f(v2.w) + bf2f(v3.w);
    }
    for (; e < end; e++) {
        short4 v0 = *(const short4*)(hb + (size_t)bucket[e] * 256 + lane * 4);
        a0 += bf2f(v0.x); a1 += bf2f(v0.y); a2 += bf2f(v0.z); a3 += bf2f(v0.w);
    }
    float nd = norm_dst[node];
    float4 bb = *(const float4*)(b1 + lane * 4);
    float o0 = fmaxf(a0 * nd + bb.x, 0.f);
    float o1 = fmaxf(a1 * nd + bb.y, 0.f);
    float o2 = fmaxf(a2 * nd + bb.z, 0.f);
    float o3 = fmaxf(a3 * nd + bb.w, 0.f);
    float4 w = *(const float4*)(W2 + lane * 4);
    float p = o0 * w.x + o1 * w.y + o2 * w.z + o3 * w.w;
#pragma unroll
    for (int off = 32; off > 0; off >>= 1) p += __shfl_xor(p, off, 64);
    if (lane == 0) z[node] = p * norm_src[node];
}

// ---------- agg2: out = relu(norm_dst * sum z[src] + b2) ----------
__global__ void agg2_kernel(const float* __restrict__ z, const int* __restrict__ bucket,
                            const int* __restrict__ offsets, const float* __restrict__ norm_dst,
                            const float* __restrict__ b2, float* __restrict__ out, int N) {
    int i = blockIdx.x * blockDim.x + threadIdx.x;
    if (i >= N) return;
    int beg = offsets[i], end = offsets[i + 1];
    float s = 0.f;
    for (int e = beg; e < end; e++) s += z[bucket[e]];
    out[i] = fmaxf(s * norm_dst[i] + b2[0], 0.f);
}

extern "C" void kernel_launch(void* const* d_in, const int* in_sizes, int n_in,
                              void* d_out, int out_size, void* d_ws, size_t ws_size,
                              hipStream_t stream) {
    const int D_HID = in_sizes[4];           // 256
    const int D_IN  = in_sizes[3] / D_HID;   // 1024
    const int N     = in_sizes[0] / D_IN;    // 50000
    const int E     = in_sizes[1];           // 800000

    const float* x   = (const float*)d_in[0];
    const int*   src = (const int*)d_in[1];
    const int*   dst = (const int*)d_in[2];
    const float* W1  = (const float*)d_in[3];
    const float* b1  = (const float*)d_in[4];
    const float* W2  = (const float*)d_in[5];
    const float* b2  = (const float*)d_in[6];
    float* out = (float*)d_out;

    char* p = (char*)d_ws;
    auto alloc = [&](size_t bytes) {
        void* r = (void*)p;
        p += (bytes + 255) & ~(size_t)255;
        return r;
    };
    int*   deg_out  = (int*)alloc((size_t)N * 4);
    int*   deg_in   = (int*)alloc((size_t)N * 4);
    int*   cursor   = (int*)alloc((size_t)N * 4);
    float* norm_src = (float*)alloc((size_t)N * 4);
    float* norm_dst = (float*)alloc((size_t)N * 4);
    int*   offsets  = (int*)alloc((size_t)(N + 1) * 4);
    int*   bucket   = (int*)alloc((size_t)E * 4);
    short* Wt       = (short*)alloc((size_t)D_IN * D_HID * 2);
    short* hb       = (short*)alloc((size_t)N * D_HID * 2);
    float* z        = (float*)alloc((size_t)N * 4);
    int*   bsum     = (int*)alloc(256 * 4);
    int*   bsum_ex  = (int*)alloc(256 * 4);

    const int NB = (N + 255) / 256;  // 196 scan blocks

    hipMemsetAsync(deg_out, 0, (size_t)N * 4, stream);
    hipMemsetAsync(deg_in,  0, (size_t)N * 4, stream);
    hipMemsetAsync(cursor,  0, (size_t)N * 4, stream);

    deg_kernel<<<(E + 255) / 256, 256, 0, stream>>>(src, dst, deg_out, deg_in, E);
    norm_kernel<<<(N + 255) / 256, 256, 0, stream>>>(deg_out, deg_in, norm_src, norm_dst, N);
    scan_part1<<<NB, 256, 0, stream>>>(deg_in, bsum, N);
    scan_part2<<<1, 256, 0, stream>>>(bsum, bsum_ex, NB, offsets, N, E);
    scan_part3<<<NB, 256, 0, stream>>>(deg_in, bsum_ex, offsets, N);
    scatter_kernel<<<(E + 255) / 256, 256, 0, stream>>>(src, dst, offsets, cursor, bucket, E);
    transpose_w1<<<dim3(D_IN / 32, D_HID / 32), 1024, 0, stream>>>(W1, Wt);
    gemm1_kernel<<<dim3((N + BM - 1) / BM, D_HID / BN), 256, 0, stream>>>(x, Wt, norm_src, hb, N);
    agg1_kernel<<<(N + 3) / 4, 256, 0, stream>>>(hb, bucket, offsets, norm_dst, norm_src, b1, W2, z, N);
    agg2_kernel<<<(N + 255) / 256, 256, 0, stream>>>(z, bucket, offsets, norm_dst, b2, out, N);
}